// Round 1
// baseline (138.339 us; speedup 1.0000x reference)
//
#include <hip/hip_runtime.h>
#include <hip/hip_bf16.h>

typedef __bf16 bf16x8 __attribute__((ext_vector_type(8)));
typedef float  f32x4  __attribute__((ext_vector_type(4)));

#define VOCAB 24
#define EDIM  16
#define HDIM  32
#define TLEN  128

__device__ __forceinline__ float fast_sig(float x) {
    // sigmoid(x) = 1 / (1 + 2^(-x*log2(e)))
    float t = __builtin_amdgcn_exp2f(x * -1.44269504f);
    return __builtin_amdgcn_rcpf(1.0f + t);
}
__device__ __forceinline__ float fast_tanh(float x) {
    // tanh(x) = 2/(1+2^(-2x*log2(e))) - 1   (saturates correctly at +/-inf)
    float t = __builtin_amdgcn_exp2f(x * -2.88539008f);
    return __builtin_amdgcn_rcpf(1.0f + t) * 2.0f - 1.0f;
}

// One wave (64 threads) per 16 batch rows.
// gates[16][128] = h[16][32] @ W_hh^T  +  onehot(x)[16][32] @ table[32][128]
// via 2x mfma_f32_16x16x32_bf16 per 16-gate column tile (8 tiles).
__global__ __launch_bounds__(64) void lstm_fused(
    const int*   __restrict__ x,     // [B][128]
    const float* __restrict__ emb,   // [24][16]
    const float* __restrict__ W_ih,  // [128][16]
    const float* __restrict__ W_hh,  // [128][32]
    const float* __restrict__ b_ih,  // [128]
    const float* __restrict__ b_hh,  // [128]
    const float* __restrict__ fc_w,  // [2][32]
    const float* __restrict__ fc_b,  // [2]
    float*       __restrict__ out)   // [B][2]
{
    __shared__ __bf16 hbuf[2][16][40];   // h double-buffer, 80B row stride (16B aligned)
    __shared__ float  fbuf[16][33];      // final h (f32) for FC epilogue

    const int lane  = threadIdx.x;       // 0..63
    const int l15   = lane & 15;
    const int hi    = lane >> 4;         // 0..3
    const int kbase = hi * 8;            // k-offset of this lane's A/B fragment
    const int row0  = blockIdx.x * 16;   // first batch row of this wave

    // ---- startup: W_hh^T B-fragments and gate-table B-fragments (registers) ----
    // B-frag layout: n = l15 + 16*nt, k = kbase + i
    bf16x8 b1f[8];  // W_hh^T : B1[k=j][g] = W_hh[g][j]
    bf16x8 b2f[8];  // table  : B2[k=v][g] = emb[v].W_ih[g] + b_ih[g]+b_hh[g] (v<24), else 0
    #pragma unroll
    for (int nt = 0; nt < 8; ++nt) {
        const int g = nt * 16 + l15;
        const float* wrow = W_hh + g * HDIM;
        #pragma unroll
        for (int i = 0; i < 8; ++i)
            b1f[nt][i] = (__bf16)wrow[kbase + i];
        const float bias = b_ih[g] + b_hh[g];
        const float* wi = W_ih + g * EDIM;
        #pragma unroll
        for (int i = 0; i < 8; ++i) {
            const int v = kbase + i;
            float s = 0.0f;
            if (v < VOCAB) {
                s = bias;
                #pragma unroll
                for (int e = 0; e < EDIM; ++e)
                    s += emb[v * EDIM + e] * wi[e];
            }
            b2f[nt][i] = (__bf16)s;
        }
    }

    const int* xrow = x + (row0 + l15) * TLEN;  // A-row of this lane = l15

    f32x4 acc[8];
    float c[8];
    #pragma unroll
    for (int q = 0; q < 8; ++q) c[q] = 0.0f;

    int4 xq;
    for (int t = 0; t < TLEN; ++t) {
        if ((t & 3) == 0) xq = *(const int4*)(xrow + t);
        const int xv = (t & 1) ? ((t & 2) ? xq.w : xq.y)
                               : ((t & 2) ? xq.z : xq.x);

        // one-hot A2 fragment: A2[row=l15][k] = (k == x[row][t]) ? 1 : 0
        bf16x8 a2;
        #pragma unroll
        for (int i = 0; i < 8; ++i)
            a2[i] = (kbase + i == xv) ? (__bf16)1.0f : (__bf16)0.0f;

        bf16x8 a1;
        if (t > 0) {               // uniform branch
            __syncthreads();       // h writes of step t-1 visible
            a1 = *(const bf16x8*)&hbuf[(t - 1) & 1][l15][kbase];
        }

        const f32x4 z = {0.f, 0.f, 0.f, 0.f};
        #pragma unroll
        for (int nt = 0; nt < 8; ++nt) {
            f32x4 a = __builtin_amdgcn_mfma_f32_16x16x32_bf16(a2, b2f[nt], z, 0, 0, 0);
            if (t > 0)
                a = __builtin_amdgcn_mfma_f32_16x16x32_bf16(a1, b1f[nt], a, 0, 0, 0);
            acc[nt] = a;
        }

        // ---- lane-local LSTM update ----
        // acc value (nt, r): gate col = 16*nt + l15, batch row = 4*hi + r
        // i: nt 0,1   f: nt 2,3   g: nt 4,5   o: nt 6,7  -> same (lane, r) across quadrants
        #pragma unroll
        for (int q = 0; q < 2; ++q) {
            #pragma unroll
            for (int r = 0; r < 4; ++r) {
                const float iv = fast_sig (acc[q    ][r]);
                const float fv = fast_sig (acc[q + 2][r]);
                const float gv = fast_tanh(acc[q + 4][r]);
                const float ov = fast_sig (acc[q + 6][r]);
                const float cc = fv * c[q * 4 + r] + iv * gv;
                c[q * 4 + r] = cc;
                const float hv = ov * fast_tanh(cc);
                hbuf[t & 1][hi * 4 + r][q * 16 + l15] = (__bf16)hv;
                if (t == TLEN - 1)
                    fbuf[hi * 4 + r][q * 16 + l15] = hv;  // exact f32 for FC
            }
        }
    }

    __syncthreads();

    // ---- FC epilogue: out[b] = h_last[b] @ fc_w^T + fc_b  (lanes 0..15) ----
    if (lane < 16) {
        float o0 = fc_b[0], o1 = fc_b[1];
        #pragma unroll
        for (int j = 0; j < HDIM; ++j) {
            const float h = fbuf[lane][j];
            o0 += fc_w[j]        * h;
            o1 += fc_w[HDIM + j] * h;
        }
        float2 res = {o0, o1};
        *(float2*)&out[(row0 + lane) * 2] = res;
    }
}

extern "C" void kernel_launch(void* const* d_in, const int* in_sizes, int n_in,
                              void* d_out, int out_size, void* d_ws, size_t ws_size,
                              hipStream_t stream) {
    const int*   x    = (const int*)  d_in[0];
    const float* emb  = (const float*)d_in[1];
    const float* W_ih = (const float*)d_in[2];
    const float* W_hh = (const float*)d_in[3];
    const float* b_ih = (const float*)d_in[4];
    const float* b_hh = (const float*)d_in[5];
    const float* fc_w = (const float*)d_in[6];
    const float* fc_b = (const float*)d_in[7];
    float* out = (float*)d_out;

    const int B = in_sizes[0] / TLEN;        // 16384
    const int nblk = B / 16;                 // 1024 waves, 1 per SIMD chip-wide

    lstm_fused<<<nblk, 64, 0, stream>>>(x, emb, W_ih, W_hh, b_ih, b_hh, fc_w, fc_b, out);
}